// Round 8
// baseline (26918.076 us; speedup 1.0000x reference)
//
#include <hip/hip_runtime.h>
#include <stdint.h>
#include <math.h>

#define TT 256
#define VOCAB 32000
#define LN_EPS 1e-5
#define NBLK 192

typedef __attribute__((ext_vector_type(8))) short bf16x8;
typedef __attribute__((ext_vector_type(4))) float f32x4;

__device__ __forceinline__ float bf2f(short s) {
  return __uint_as_float(((uint32_t)(uint16_t)s) << 16);
}
__device__ __forceinline__ short f2bf(float f) {
  uint32_t u = __float_as_uint(f);
  u += 0x7fffu + ((u >> 16) & 1u);
  return (short)(u >> 16);
}
__device__ __forceinline__ f32x4 mfma16(bf16x8 a, bf16x8 b, f32x4 c) {
  return __builtin_amdgcn_mfma_f32_16x16x32_bf16(a, b, c, 0, 0, 0);
}

// ---------------- gi0 = embd[input] @ Wih0^T + bih0, f64, fully parallel ----------------
__global__ void k_gi0(const int* __restrict__ input, const float* __restrict__ embd,
                      const float* __restrict__ Wih0, const float* __restrict__ bih0,
                      double* __restrict__ gi0) {
  const int t = blockIdx.x >> 4;
  const int cg = blockIdx.x & 15;
  const int tid = threadIdx.x;
  __shared__ float xs[16][512];
  for (int idx = tid; idx < 16 * 512; idx += 256) {
    const int r = idx >> 9, j = idx & 511;
    const int tok = input[r * TT + t];
    xs[r][j] = embd[(size_t)tok * 512 + j];
  }
  __syncthreads();
  const int row = tid >> 4, ct = tid & 15;
  for (int i = 0; i < 12; ++i) {
    const int c = cg * 192 + ct + 16 * i;
    const float4* wp = (const float4*)(Wih0 + (size_t)c * 512);
    const float4* xp = (const float4*)&xs[row][0];
    double acc = 0.0;
#pragma unroll 8
    for (int j4 = 0; j4 < 128; ++j4) {
      const float4 w = wp[j4];
      const float4 x = xp[j4];
      acc = fma((double)x.x, (double)w.x, acc);
      acc = fma((double)x.y, (double)w.y, acc);
      acc = fma((double)x.z, (double)w.z, acc);
      acc = fma((double)x.w, (double)w.w, acc);
    }
    gi0[((size_t)t * 16 + row) * 3072 + c] = acc + (double)bih0[c];
  }
}

// ---------------- persistent recurrence: 257 phases, 1 launch, grid barrier ----------------
// grid 192 x 512: blocks 0..63 layer0 (16 cols each), 64..191 layer1 (8 cols each).
// block 512 = 16 rows x 32 ks. All blocks co-resident (1 block/CU, 2 waves/SIMD,
// <=256 VGPR via __launch_bounds__(512,1) -- the (512,2) bound in round 7 capped
// VGPR at 128 and spilled the 128-VGPR a0/a1 arrays to scratch).
struct SP {
  const float *Whh0, *bhh0, *ln0w, *ln0b;
  const float *Wih1, *Whh1, *bih1, *bhh1, *ln1w, *ln1b;
  const double* gi0;
  double *h0ring, *h1ring;  // [2][16][1024] f64 raw hidden states
  float* h1hist;            // [256*16][1024] f32 raw h1 history
  int* bar;
};

__launch_bounds__(512, 1)
__global__ void k_recur(SP A) {
  __shared__ double sPre[16 * 16 * 3];  // L0: [row][16 cols][3]; L1: [row][8 cols][6]
  __shared__ double sM[16], sR[16];
  const int tid = threadIdx.x;
  const int row = tid >> 5;
  const int ks = tid & 31;
  const int bid = blockIdx.x;

  for (int p = 0; p <= TT; ++p) {
    if (bid < 64) {
      // ================= layer0, t = p =================
      const int t = p;
      if (t < TT) {
        const int col0 = bid * 16;
        double a[32];
        if (t > 0) {
          const double* hp = A.h0ring + (size_t)((t - 1) & 1) * 16384 + row * 1024;
          double s = 0.0, q = 0.0;
#pragma unroll
          for (int g = 0; g < 8; ++g)
#pragma unroll
            for (int u = 0; u < 4; ++u) {
              const double v = hp[g * 128 + ks * 4 + u];
              a[g * 4 + u] = v; s += v; q += v * v;
            }
#pragma unroll
          for (int mk = 1; mk <= 16; mk <<= 1) { s += __shfl_xor(s, mk); q += __shfl_xor(q, mk); }
          const double m = s * (1.0 / 1024.0);
          const double rs = 1.0 / sqrt(q * (1.0 / 1024.0) - m * m + LN_EPS);
          if (ks == 0) { sM[row] = m; sR[row] = rs; }
#pragma unroll
          for (int g = 0; g < 8; ++g) {
            const float4 lw = *(const float4*)(A.ln0w + g * 128 + ks * 4);
            const float4 lb = *(const float4*)(A.ln0b + g * 128 + ks * 4);
            a[g * 4 + 0] = (a[g * 4 + 0] - m) * rs * (double)lw.x + (double)lb.x;
            a[g * 4 + 1] = (a[g * 4 + 1] - m) * rs * (double)lw.y + (double)lb.y;
            a[g * 4 + 2] = (a[g * 4 + 2] - m) * rs * (double)lw.z + (double)lb.z;
            a[g * 4 + 3] = (a[g * 4 + 3] - m) * rs * (double)lw.w + (double)lb.w;
          }
          for (int cc = 0; cc < 16; ++cc) {
            const int c = col0 + cc;
            const float4* pr = (const float4*)(A.Whh0 + (size_t)c * 1024);
            const float4* pz = (const float4*)(A.Whh0 + (size_t)(c + 1024) * 1024);
            const float4* pn = (const float4*)(A.Whh0 + (size_t)(c + 2048) * 1024);
            double ar = 0.0, az = 0.0, an_ = 0.0;
#pragma unroll
            for (int g = 0; g < 8; ++g) {
              const int o = g * 32 + ks;
              const float4 wr = pr[o], wz = pz[o], wn = pn[o];
              ar = fma(a[g*4+0], (double)wr.x, ar); ar = fma(a[g*4+1], (double)wr.y, ar);
              ar = fma(a[g*4+2], (double)wr.z, ar); ar = fma(a[g*4+3], (double)wr.w, ar);
              az = fma(a[g*4+0], (double)wz.x, az); az = fma(a[g*4+1], (double)wz.y, az);
              az = fma(a[g*4+2], (double)wz.z, az); az = fma(a[g*4+3], (double)wz.w, az);
              an_ = fma(a[g*4+0], (double)wn.x, an_); an_ = fma(a[g*4+1], (double)wn.y, an_);
              an_ = fma(a[g*4+2], (double)wn.z, an_); an_ = fma(a[g*4+3], (double)wn.w, an_);
            }
#pragma unroll
            for (int mk = 1; mk <= 16; mk <<= 1) {
              ar += __shfl_xor(ar, mk); az += __shfl_xor(az, mk); an_ += __shfl_xor(an_, mk);
            }
            if (ks == 0) {
              sPre[(row * 16 + cc) * 3 + 0] = ar;
              sPre[(row * 16 + cc) * 3 + 1] = az;
              sPre[(row * 16 + cc) * 3 + 2] = an_;
            }
          }
        } else {
          if (tid < 256) {
            sPre[tid * 3 + 0] = 0.0; sPre[tid * 3 + 1] = 0.0; sPre[tid * 3 + 2] = 0.0;
          }
        }
        __syncthreads();
        if (tid < 256) {
          const int r2 = tid >> 4, cc = tid & 15;
          const int c = col0 + cc;
          const double ghr = sPre[(r2 * 16 + cc) * 3 + 0] + (double)A.bhh0[c];
          const double ghz = sPre[(r2 * 16 + cc) * 3 + 1] + (double)A.bhh0[c + 1024];
          const double ghn = sPre[(r2 * 16 + cc) * 3 + 2] + (double)A.bhh0[c + 2048];
          const double* gp = A.gi0 + ((size_t)t * 16 + r2) * 3072 + c;
          const double gir = gp[0], giz = gp[1024], gin = gp[2048];
          const double rg = 1.0 / (1.0 + exp(-(gir + ghr)));
          const double zg = 1.0 / (1.0 + exp(-(giz + ghz)));
          const double ng = tanh(gin + rg * ghn);
          double hprev = 0.0;
          if (t > 0) {
            const double praw = A.h0ring[(size_t)((t - 1) & 1) * 16384 + r2 * 1024 + c];
            hprev = (praw - sM[r2]) * sR[r2] * (double)A.ln0w[c] + (double)A.ln0b[c];
          }
          A.h0ring[(size_t)(t & 1) * 16384 + r2 * 1024 + c] = (1.0 - zg) * ng + zg * hprev;
        }
      }
    } else {
      // ================= layer1, t = p-1 =================
      const int t = p - 1;
      if (t >= 0 && t < TT) {
        const int col0 = (bid - 64) * 8;
        double a0[32], a1[32];
        {
          const double* hp = A.h0ring + (size_t)(t & 1) * 16384 + row * 1024;
          double s = 0.0, q = 0.0;
#pragma unroll
          for (int g = 0; g < 8; ++g)
#pragma unroll
            for (int u = 0; u < 4; ++u) {
              const double v = hp[g * 128 + ks * 4 + u];
              a0[g * 4 + u] = v; s += v; q += v * v;
            }
#pragma unroll
          for (int mk = 1; mk <= 16; mk <<= 1) { s += __shfl_xor(s, mk); q += __shfl_xor(q, mk); }
          const double m = s * (1.0 / 1024.0);
          const double rs = 1.0 / sqrt(q * (1.0 / 1024.0) - m * m + LN_EPS);
#pragma unroll
          for (int g = 0; g < 8; ++g) {
            const float4 lw = *(const float4*)(A.ln0w + g * 128 + ks * 4);
            const float4 lb = *(const float4*)(A.ln0b + g * 128 + ks * 4);
            a0[g * 4 + 0] = (a0[g * 4 + 0] - m) * rs * (double)lw.x + (double)lb.x;
            a0[g * 4 + 1] = (a0[g * 4 + 1] - m) * rs * (double)lw.y + (double)lb.y;
            a0[g * 4 + 2] = (a0[g * 4 + 2] - m) * rs * (double)lw.z + (double)lb.z;
            a0[g * 4 + 3] = (a0[g * 4 + 3] - m) * rs * (double)lw.w + (double)lb.w;
          }
        }
        if (t > 0) {
          const double* hp = A.h1ring + (size_t)((t - 1) & 1) * 16384 + row * 1024;
          double s = 0.0, q = 0.0;
#pragma unroll
          for (int g = 0; g < 8; ++g)
#pragma unroll
            for (int u = 0; u < 4; ++u) {
              const double v = hp[g * 128 + ks * 4 + u];
              a1[g * 4 + u] = v; s += v; q += v * v;
            }
#pragma unroll
          for (int mk = 1; mk <= 16; mk <<= 1) { s += __shfl_xor(s, mk); q += __shfl_xor(q, mk); }
          const double m = s * (1.0 / 1024.0);
          const double rs = 1.0 / sqrt(q * (1.0 / 1024.0) - m * m + LN_EPS);
          if (ks == 0) { sM[row] = m; sR[row] = rs; }
#pragma unroll
          for (int g = 0; g < 8; ++g) {
            const float4 lw = *(const float4*)(A.ln1w + g * 128 + ks * 4);
            const float4 lb = *(const float4*)(A.ln1b + g * 128 + ks * 4);
            a1[g * 4 + 0] = (a1[g * 4 + 0] - m) * rs * (double)lw.x + (double)lb.x;
            a1[g * 4 + 1] = (a1[g * 4 + 1] - m) * rs * (double)lw.y + (double)lb.y;
            a1[g * 4 + 2] = (a1[g * 4 + 2] - m) * rs * (double)lw.z + (double)lb.z;
            a1[g * 4 + 3] = (a1[g * 4 + 3] - m) * rs * (double)lw.w + (double)lb.w;
          }
        } else {
#pragma unroll
          for (int j = 0; j < 32; ++j) a1[j] = 0.0;
        }
        for (int cc = 0; cc < 8; ++cc) {
          const int c = col0 + cc;
          const float4* ir = (const float4*)(A.Wih1 + (size_t)c * 1024);
          const float4* iz = (const float4*)(A.Wih1 + (size_t)(c + 1024) * 1024);
          const float4* in_ = (const float4*)(A.Wih1 + (size_t)(c + 2048) * 1024);
          const float4* hr = (const float4*)(A.Whh1 + (size_t)c * 1024);
          const float4* hz = (const float4*)(A.Whh1 + (size_t)(c + 1024) * 1024);
          const float4* hn = (const float4*)(A.Whh1 + (size_t)(c + 2048) * 1024);
          double sIr = 0.0, sIz = 0.0, sIn = 0.0, sHr = 0.0, sHz = 0.0, sHn = 0.0;
#pragma unroll
          for (int g = 0; g < 8; ++g) {
            const int o = g * 32 + ks;
            const float4 w0 = ir[o], w1 = iz[o], w2 = in_[o];
            const float4 w3 = hr[o], w4 = hz[o], w5 = hn[o];
            sIr = fma(a0[g*4+0], (double)w0.x, sIr); sIr = fma(a0[g*4+1], (double)w0.y, sIr);
            sIr = fma(a0[g*4+2], (double)w0.z, sIr); sIr = fma(a0[g*4+3], (double)w0.w, sIr);
            sIz = fma(a0[g*4+0], (double)w1.x, sIz); sIz = fma(a0[g*4+1], (double)w1.y, sIz);
            sIz = fma(a0[g*4+2], (double)w1.z, sIz); sIz = fma(a0[g*4+3], (double)w1.w, sIz);
            sIn = fma(a0[g*4+0], (double)w2.x, sIn); sIn = fma(a0[g*4+1], (double)w2.y, sIn);
            sIn = fma(a0[g*4+2], (double)w2.z, sIn); sIn = fma(a0[g*4+3], (double)w2.w, sIn);
            sHr = fma(a1[g*4+0], (double)w3.x, sHr); sHr = fma(a1[g*4+1], (double)w3.y, sHr);
            sHr = fma(a1[g*4+2], (double)w3.z, sHr); sHr = fma(a1[g*4+3], (double)w3.w, sHr);
            sHz = fma(a1[g*4+0], (double)w4.x, sHz); sHz = fma(a1[g*4+1], (double)w4.y, sHz);
            sHz = fma(a1[g*4+2], (double)w4.z, sHz); sHz = fma(a1[g*4+3], (double)w4.w, sHz);
            sHn = fma(a1[g*4+0], (double)w5.x, sHn); sHn = fma(a1[g*4+1], (double)w5.y, sHn);
            sHn = fma(a1[g*4+2], (double)w5.z, sHn); sHn = fma(a1[g*4+3], (double)w5.w, sHn);
          }
#pragma unroll
          for (int mk = 1; mk <= 16; mk <<= 1) {
            sIr += __shfl_xor(sIr, mk); sIz += __shfl_xor(sIz, mk); sIn += __shfl_xor(sIn, mk);
            sHr += __shfl_xor(sHr, mk); sHz += __shfl_xor(sHz, mk); sHn += __shfl_xor(sHn, mk);
          }
          if (ks == 0) {
            double* pp = &sPre[(row * 8 + cc) * 6];
            pp[0] = sIr; pp[1] = sIz; pp[2] = sIn; pp[3] = sHr; pp[4] = sHz; pp[5] = sHn;
          }
        }
        __syncthreads();
        if (tid < 128) {
          const int r2 = tid >> 3, cc = tid & 7;
          const int c = col0 + cc;
          const double* pp = &sPre[(r2 * 8 + cc) * 6];
          const double gir = pp[0] + (double)A.bih1[c];
          const double giz = pp[1] + (double)A.bih1[c + 1024];
          const double gin = pp[2] + (double)A.bih1[c + 2048];
          const double ghr = pp[3] + (double)A.bhh1[c];
          const double ghz = pp[4] + (double)A.bhh1[c + 1024];
          const double ghn = pp[5] + (double)A.bhh1[c + 2048];
          const double rg = 1.0 / (1.0 + exp(-(gir + ghr)));
          const double zg = 1.0 / (1.0 + exp(-(giz + ghz)));
          const double ng = tanh(gin + rg * ghn);
          double hprev = 0.0;
          if (t > 0) {
            const double praw = A.h1ring[(size_t)((t - 1) & 1) * 16384 + r2 * 1024 + c];
            hprev = (praw - sM[r2]) * sR[r2] * (double)A.ln1w[c] + (double)A.ln1b[c];
          }
          const double hnew = (1.0 - zg) * ng + zg * hprev;
          A.h1ring[(size_t)(t & 1) * 16384 + r2 * 1024 + c] = hnew;
          A.h1hist[((size_t)t * 16 + r2) * 1024 + c] = (float)hnew;
        }
      }
    }

    // ---------- grid barrier ----------
    __syncthreads();
    if (tid == 0) {
      __threadfence();
      __hip_atomic_fetch_add(A.bar, 1, __ATOMIC_ACQ_REL, __HIP_MEMORY_SCOPE_AGENT);
      const int target = NBLK * (p + 1);
      while (__hip_atomic_load(A.bar, __ATOMIC_ACQUIRE, __HIP_MEMORY_SCOPE_AGENT) < target) {
        __builtin_amdgcn_s_sleep(8);
      }
      __threadfence();
    }
    __syncthreads();
  }
}

// ---------------- batched head pre-proj (byte-identical to round 7) ----------------
__launch_bounds__(512, 2)
__global__ void k_headpre(const float* __restrict__ h1hist, const float* __restrict__ ln1w,
                          const float* __restrict__ ln1b, const float* __restrict__ W1,
                          const float* __restrict__ b1, short* __restrict__ araw) {
  const int tid = threadIdx.x;
  const int row = tid >> 5, ks = tid & 31;
  const size_t m = (size_t)blockIdx.x * 16 + row;
  const float* hp = h1hist + m * 1024;
  float a[32];
  float s = 0.f, q = 0.f;
#pragma unroll
  for (int g = 0; g < 8; ++g) {
    const float4 v = *(const float4*)(hp + g * 128 + ks * 4);
    a[g*4+0] = v.x; a[g*4+1] = v.y; a[g*4+2] = v.z; a[g*4+3] = v.w;
    s += v.x + v.y + v.z + v.w;
    q += v.x * v.x + v.y * v.y + v.z * v.z + v.w * v.w;
  }
#pragma unroll
  for (int mk = 1; mk <= 16; mk <<= 1) { s += __shfl_xor(s, mk); q += __shfl_xor(q, mk); }
  const float mn = s * (1.f / 1024.f);
  const float rs = rsqrtf(q * (1.f / 1024.f) - mn * mn + 1e-5f);
#pragma unroll
  for (int g = 0; g < 8; ++g) {
    const float4 lw = *(const float4*)(ln1w + g * 128 + ks * 4);
    const float4 lb = *(const float4*)(ln1b + g * 128 + ks * 4);
    a[g*4+0] = (a[g*4+0] - mn) * rs * lw.x + lb.x;
    a[g*4+1] = (a[g*4+1] - mn) * rs * lw.y + lb.y;
    a[g*4+2] = (a[g*4+2] - mn) * rs * lw.z + lb.z;
    a[g*4+3] = (a[g*4+3] - mn) * rs * lw.w + lb.w;
  }
  for (int c = 0; c < 1024; ++c) {
    const float4* wp = (const float4*)(W1 + (size_t)c * 1024);
    float acc = 0.f;
#pragma unroll
    for (int g = 0; g < 8; ++g) {
      const float4 w = wp[g * 32 + ks];
      acc = fmaf(a[g*4+0], w.x, acc); acc = fmaf(a[g*4+1], w.y, acc);
      acc = fmaf(a[g*4+2], w.z, acc); acc = fmaf(a[g*4+3], w.w, acc);
    }
#pragma unroll
    for (int mk = 1; mk <= 16; mk <<= 1) acc += __shfl_xor(acc, mk);
    if (ks == 0) {
      const float y = acc + b1[c];
      araw[m * 1024 + c] = f2bf(y > 0.f ? y : 0.01f * y);
    }
  }
}

// ---------------- head GEMM (byte-identical to round 6/7) ----------------
__global__ void k_head(const short* __restrict__ araw, const float* __restrict__ W2,
                       const float* __restrict__ ln2w, const float* __restrict__ ln2b,
                       const float* __restrict__ b2, float* __restrict__ C) {
  __shared__ __align__(16) short As[128 * 64];
  __shared__ __align__(16) short Bs[128 * 64];
  __shared__ float rowm[128], rowr[128];
  __shared__ float lnw_s[1024], lnb_s[1024];
  __shared__ float ps[256], pq[256];
  const int tid = threadIdx.x;
  const long brow = (long)blockIdx.y * 128;
  const long bcol = (long)blockIdx.x * 128;

  for (int i = tid; i < 1024; i += 256) { lnw_s[i] = ln2w[i]; lnb_s[i] = ln2b[i]; }
  {
    const int r2 = tid >> 1, hf = tid & 1;
    const short* ap = araw + (brow + r2) * 1024 + hf * 512;
    float s = 0.f, q = 0.f;
    for (int j = 0; j < 512; j += 8) {
      const bf16x8 v = *(const bf16x8*)(ap + j);
#pragma unroll
      for (int e = 0; e < 8; ++e) { const float x = bf2f(v[e]); s += x; q += x * x; }
    }
    ps[tid] = s; pq[tid] = q;
  }
  __syncthreads();
  if (tid < 128) {
    const float s = ps[2 * tid] + ps[2 * tid + 1];
    const float q = pq[2 * tid] + pq[2 * tid + 1];
    const float m = s * (1.f / 1024.f);
    rowm[tid] = m;
    rowr[tid] = rsqrtf(q * (1.f / 1024.f) - m * m + 1e-5f);
  }
  __syncthreads();

  const int l = tid & 63;
  const int w = tid >> 6;
  const int wm = w >> 1, wn = w & 1;
  const int lane15 = l & 15, lgrp = l >> 4;
  f32x4 zero4 = {0.f, 0.f, 0.f, 0.f};
  f32x4 acc[4][4];
#pragma unroll
  for (int ri = 0; ri < 4; ++ri)
#pragma unroll
    for (int ci = 0; ci < 4; ++ci) acc[ri][ci] = zero4;

  for (int k0 = 0; k0 < 1024; k0 += 64) {
    __syncthreads();
#pragma unroll
    for (int i = 0; i < 4; ++i) {
      const int c = tid + i * 256;
      const int r = c >> 3, cc = c & 7;
      const int k = k0 + cc * 8;
      {
        const bf16x8 v = *(const bf16x8*)(araw + (brow + r) * 1024 + k);
        const float mm = rowm[r], rr = rowr[r];
        bf16x8 o;
#pragma unroll
        for (int e = 0; e < 8; ++e)
          o[e] = f2bf((bf2f(v[e]) - mm) * rr * lnw_s[k + e] + lnb_s[k + e]);
        *(bf16x8*)&As[r * 64 + cc * 8] = o;
      }
      {
        const float4* bp = (const float4*)(W2 + (bcol + r) * 1024 + k);
        const float4 v0 = bp[0], v1 = bp[1];
        bf16x8 o;
        o[0] = f2bf(v0.x); o[1] = f2bf(v0.y); o[2] = f2bf(v0.z); o[3] = f2bf(v0.w);
        o[4] = f2bf(v1.x); o[5] = f2bf(v1.y); o[6] = f2bf(v1.z); o[7] = f2bf(v1.w);
        *(bf16x8*)&Bs[r * 64 + cc * 8] = o;
      }
    }
    __syncthreads();
#pragma unroll
    for (int kk = 0; kk < 2; ++kk) {
      const int ko = kk * 32 + lgrp * 8;
      bf16x8 av[4], bv[4];
#pragma unroll
      for (int ri = 0; ri < 4; ++ri) av[ri] = *(const bf16x8*)&As[(wm * 64 + ri * 16 + lane15) * 64 + ko];
#pragma unroll
      for (int ci = 0; ci < 4; ++ci) bv[ci] = *(const bf16x8*)&Bs[(wn * 64 + ci * 16 + lane15) * 64 + ko];
#pragma unroll
      for (int ri = 0; ri < 4; ++ri)
#pragma unroll
        for (int ci = 0; ci < 4; ++ci) acc[ri][ci] = mfma16(av[ri], bv[ci], acc[ri][ci]);
    }
  }
#pragma unroll
  for (int ri = 0; ri < 4; ++ri)
#pragma unroll
    for (int ci = 0; ci < 4; ++ci)
#pragma unroll
      for (int i = 0; i < 4; ++i) {
        const long mrow = brow + wm * 64 + ri * 16 + lgrp * 4 + i;
        const long ncol = bcol + wn * 64 + ci * 16 + lane15;
        const int tq = (int)(mrow >> 4), b = (int)(mrow & 15);
        C[(size_t)b * TT * VOCAB + (size_t)tq * VOCAB + ncol] = acc[ri][ci][i] + b2[ncol];
      }
}

// ---------------- host launch ----------------
extern "C" void kernel_launch(void* const* d_in, const int* in_sizes, int n_in,
                              void* d_out, int out_size, void* d_ws, size_t ws_size,
                              hipStream_t stream) {
  const int* input = (const int*)d_in[0];
  const float* embd = (const float*)d_in[1];
  const float* Wih0 = (const float*)d_in[2];
  const float* Whh0 = (const float*)d_in[3];
  const float* bih0 = (const float*)d_in[4];
  const float* bhh0 = (const float*)d_in[5];
  const float* ln0w = (const float*)d_in[6];
  const float* ln0b = (const float*)d_in[7];
  const float* Wih1 = (const float*)d_in[8];
  const float* Whh1 = (const float*)d_in[9];
  const float* bih1 = (const float*)d_in[10];
  const float* bhh1 = (const float*)d_in[11];
  const float* ln1w = (const float*)d_in[12];
  const float* ln1b = (const float*)d_in[13];
  const float* W1 = (const float*)d_in[14];
  const float* b1 = (const float*)d_in[15];
  const float* ln2w = (const float*)d_in[16];
  const float* ln2b = (const float*)d_in[17];
  const float* W2 = (const float*)d_in[18];
  const float* b2 = (const float*)d_in[19];
  float* out = (float*)d_out;

  // ws (25.4 MB): rings + h1 history + araw + barrier.
  char* ws = (char*)d_ws;
  size_t off = 0;
  auto alloc = [&](size_t bytes) -> char* {
    char* p = ws + off;
    off = (off + bytes + 255) & ~(size_t)255;
    return p;
  };
  double* h0ring = (double*)alloc(2ull * 16 * 1024 * 8);
  double* h1ring = (double*)alloc(2ull * 16 * 1024 * 8);
  float* h1hist = (float*)alloc(4096ull * 1024 * 4);
  short* araw = (short*)alloc(4096ull * 1024 * 2);
  int* bar = (int*)alloc(256);

  hipMemsetAsync(bar, 0, 256, stream);

  // gi0 (100.7 MB f64) in d_out-as-scratch: fully consumed by k_recur; k_head
  // then overwrites every byte of d_out.
  double* gi0 = (double*)d_out;

  k_gi0<<<4096, 256, 0, stream>>>(input, embd, Wih0, bih0, gi0);

  SP A;
  A.Whh0 = Whh0; A.bhh0 = bhh0; A.ln0w = ln0w; A.ln0b = ln0b;
  A.Wih1 = Wih1; A.Whh1 = Whh1; A.bih1 = bih1; A.bhh1 = bhh1;
  A.ln1w = ln1w; A.ln1b = ln1b;
  A.gi0 = gi0; A.h0ring = h0ring; A.h1ring = h1ring; A.h1hist = h1hist;
  A.bar = bar;
  k_recur<<<NBLK, 512, 0, stream>>>(A);

  k_headpre<<<256, 512, 0, stream>>>(h1hist, ln1w, ln1b, W1, b1, araw);

  k_head<<<dim3(250, 32), 256, 0, stream>>>(araw, W2, ln2w, ln2b, b2, out);
}

// Round 9
// 22872.858 us; speedup vs baseline: 1.1769x; 1.1769x over previous
//
#include <hip/hip_runtime.h>
#include <stdint.h>
#include <math.h>

#define TT 256
#define VOCAB 32000
#define LN_EPS 1e-5
#define NBLK 192

typedef __attribute__((ext_vector_type(8))) short bf16x8;
typedef __attribute__((ext_vector_type(4))) float f32x4;

__device__ __forceinline__ float bf2f(short s) {
  return __uint_as_float(((uint32_t)(uint16_t)s) << 16);
}
__device__ __forceinline__ short f2bf(float f) {
  uint32_t u = __float_as_uint(f);
  u += 0x7fffu + ((u >> 16) & 1u);
  return (short)(u >> 16);
}
__device__ __forceinline__ f32x4 mfma16(bf16x8 a, bf16x8 b, f32x4 c) {
  return __builtin_amdgcn_mfma_f32_16x16x32_bf16(a, b, c, 0, 0, 0);
}

// ---------------- gi0 = embd[input] @ Wih0^T + bih0, f64, fully parallel ----------------
__global__ void k_gi0(const int* __restrict__ input, const float* __restrict__ embd,
                      const float* __restrict__ Wih0, const float* __restrict__ bih0,
                      double* __restrict__ gi0) {
  const int t = blockIdx.x >> 4;
  const int cg = blockIdx.x & 15;
  const int tid = threadIdx.x;
  __shared__ float xs[16][512];
  for (int idx = tid; idx < 16 * 512; idx += 256) {
    const int r = idx >> 9, j = idx & 511;
    const int tok = input[r * TT + t];
    xs[r][j] = embd[(size_t)tok * 512 + j];
  }
  __syncthreads();
  const int row = tid >> 4, ct = tid & 15;
  for (int i = 0; i < 12; ++i) {
    const int c = cg * 192 + ct + 16 * i;
    const float4* wp = (const float4*)(Wih0 + (size_t)c * 512);
    const float4* xp = (const float4*)&xs[row][0];
    double acc = 0.0;
#pragma unroll 8
    for (int j4 = 0; j4 < 128; ++j4) {
      const float4 w = wp[j4];
      const float4 x = xp[j4];
      acc = fma((double)x.x, (double)w.x, acc);
      acc = fma((double)x.y, (double)w.y, acc);
      acc = fma((double)x.z, (double)w.z, acc);
      acc = fma((double)x.w, (double)w.w, acc);
    }
    gi0[((size_t)t * 16 + row) * 3072 + c] = acc + (double)bih0[c];
  }
}

// ---------------- persistent recurrence: 257 phases, 1 launch, grid barrier ----------------
// grid 192 x 1024 (16 waves = 16 batch rows per block; lane l holds k-slice
// k = g*256 + l*4 + u, g<4, u<4 -> double a[16] = 32 VGPR).
// blocks 0..63: layer0, 16 cols each. blocks 64..191: layer1, 8 cols each,
// TWO-PASS (a0 pass then a1 pass) so only one 16-double array is live at a time.
// Peak live set ~100 VGPR < the 128 cap of a 1024-thread block -> no scratch
// (round 8: 128-VGPR cap + 128-VGPR arrays = spills = 23 ms).
struct SP {
  const float *Whh0, *bhh0, *ln0w, *ln0b;
  const float *Wih1, *Whh1, *bih1, *bhh1, *ln1w, *ln1b;
  const double* gi0;
  double *h0ring, *h1ring;  // [2][16][1024] f64 raw hidden states
  float* h1hist;            // [256*16][1024] f32 raw h1 history
  int* bar;
};

__launch_bounds__(1024, 1)
__global__ void k_recur(SP A) {
  const int tid = threadIdx.x;
  const int w = tid >> 6;  // batch row 0..15 (one wave per row)
  const int l = tid & 63;  // lane
  const int bid = blockIdx.x;

  for (int p = 0; p <= TT; ++p) {
    if (bid < 64) {
      // ================= layer0, t = p =================
      const int t = p;
      if (t < TT) {
        const int col0 = bid * 16;
        double sAr = 0.0, sAz = 0.0, sAn = 0.0, m = 0.0, rs = 0.0;
        if (t > 0) {
          double a[16];
          const double* hp = A.h0ring + (size_t)((t - 1) & 1) * 16384 + w * 1024;
          double s = 0.0, q = 0.0;
#pragma unroll
          for (int g = 0; g < 4; ++g) {
            const double2 x0 = *(const double2*)(hp + g * 256 + l * 4);
            const double2 x1 = *(const double2*)(hp + g * 256 + l * 4 + 2);
            a[g*4+0] = x0.x; a[g*4+1] = x0.y; a[g*4+2] = x1.x; a[g*4+3] = x1.y;
            s += x0.x + x0.y + x1.x + x1.y;
            q += x0.x*x0.x + x0.y*x0.y + x1.x*x1.x + x1.y*x1.y;
          }
#pragma unroll
          for (int mk = 1; mk <= 32; mk <<= 1) { s += __shfl_xor(s, mk); q += __shfl_xor(q, mk); }
          m = s * (1.0 / 1024.0);
          rs = 1.0 / sqrt(q * (1.0 / 1024.0) - m * m + LN_EPS);
#pragma unroll
          for (int g = 0; g < 4; ++g) {
            const float4 lw = *(const float4*)(A.ln0w + g * 256 + l * 4);
            const float4 lb = *(const float4*)(A.ln0b + g * 256 + l * 4);
            a[g*4+0] = (a[g*4+0] - m) * rs * (double)lw.x + (double)lb.x;
            a[g*4+1] = (a[g*4+1] - m) * rs * (double)lw.y + (double)lb.y;
            a[g*4+2] = (a[g*4+2] - m) * rs * (double)lw.z + (double)lb.z;
            a[g*4+3] = (a[g*4+3] - m) * rs * (double)lw.w + (double)lb.w;
          }
          for (int cc = 0; cc < 16; ++cc) {
            const int c = col0 + cc;
            const float4* pr = (const float4*)(A.Whh0 + (size_t)c * 1024);
            const float4* pz = (const float4*)(A.Whh0 + (size_t)(c + 1024) * 1024);
            const float4* pn = (const float4*)(A.Whh0 + (size_t)(c + 2048) * 1024);
            double ar = 0.0, az = 0.0, an_ = 0.0;
#pragma unroll
            for (int g = 0; g < 4; ++g) {
              const float4 wr = pr[g*64 + l], wz = pz[g*64 + l], wn = pn[g*64 + l];
              ar = fma(a[g*4+0], (double)wr.x, ar); ar = fma(a[g*4+1], (double)wr.y, ar);
              ar = fma(a[g*4+2], (double)wr.z, ar); ar = fma(a[g*4+3], (double)wr.w, ar);
              az = fma(a[g*4+0], (double)wz.x, az); az = fma(a[g*4+1], (double)wz.y, az);
              az = fma(a[g*4+2], (double)wz.z, az); az = fma(a[g*4+3], (double)wz.w, az);
              an_ = fma(a[g*4+0], (double)wn.x, an_); an_ = fma(a[g*4+1], (double)wn.y, an_);
              an_ = fma(a[g*4+2], (double)wn.z, an_); an_ = fma(a[g*4+3], (double)wn.w, an_);
            }
#pragma unroll
            for (int mk = 1; mk <= 32; mk <<= 1) {
              ar += __shfl_xor(ar, mk); az += __shfl_xor(az, mk); an_ += __shfl_xor(an_, mk);
            }
            if (l == cc) { sAr = ar; sAz = az; sAn = an_; }
          }
        }
        if (l < 16) {
          const int c = col0 + l;
          const double ghr = sAr + (double)A.bhh0[c];
          const double ghz = sAz + (double)A.bhh0[c + 1024];
          const double ghn = sAn + (double)A.bhh0[c + 2048];
          const double* gp = A.gi0 + ((size_t)t * 16 + w) * 3072 + c;
          const double gir = gp[0], giz = gp[1024], gin = gp[2048];
          const double rg = 1.0 / (1.0 + exp(-(gir + ghr)));
          const double zg = 1.0 / (1.0 + exp(-(giz + ghz)));
          const double ng = tanh(gin + rg * ghn);
          double hprev = 0.0;
          if (t > 0) {
            const double praw = A.h0ring[(size_t)((t - 1) & 1) * 16384 + w * 1024 + c];
            hprev = (praw - m) * rs * (double)A.ln0w[c] + (double)A.ln0b[c];
          }
          A.h0ring[(size_t)(t & 1) * 16384 + w * 1024 + c] = (1.0 - zg) * ng + zg * hprev;
        }
      }
    } else {
      // ================= layer1, t = p-1, two-pass =================
      const int t = p - 1;
      if (t >= 0 && t < TT) {
        const int col0 = (bid - 64) * 8;
        double sIr = 0.0, sIz = 0.0, sIn = 0.0, sHr = 0.0, sHz = 0.0, sHn = 0.0;
        double m1 = 0.0, r1 = 0.0;
        // ---- pass A: a0 = LN0(h0(t)), Wih1 dots ----
        {
          double a0[16];
          const double* hp = A.h0ring + (size_t)(t & 1) * 16384 + w * 1024;
          double s = 0.0, q = 0.0;
#pragma unroll
          for (int g = 0; g < 4; ++g) {
            const double2 x0 = *(const double2*)(hp + g * 256 + l * 4);
            const double2 x1 = *(const double2*)(hp + g * 256 + l * 4 + 2);
            a0[g*4+0] = x0.x; a0[g*4+1] = x0.y; a0[g*4+2] = x1.x; a0[g*4+3] = x1.y;
            s += x0.x + x0.y + x1.x + x1.y;
            q += x0.x*x0.x + x0.y*x0.y + x1.x*x1.x + x1.y*x1.y;
          }
#pragma unroll
          for (int mk = 1; mk <= 32; mk <<= 1) { s += __shfl_xor(s, mk); q += __shfl_xor(q, mk); }
          const double m0 = s * (1.0 / 1024.0);
          const double r0 = 1.0 / sqrt(q * (1.0 / 1024.0) - m0 * m0 + LN_EPS);
#pragma unroll
          for (int g = 0; g < 4; ++g) {
            const float4 lw = *(const float4*)(A.ln0w + g * 256 + l * 4);
            const float4 lb = *(const float4*)(A.ln0b + g * 256 + l * 4);
            a0[g*4+0] = (a0[g*4+0] - m0) * r0 * (double)lw.x + (double)lb.x;
            a0[g*4+1] = (a0[g*4+1] - m0) * r0 * (double)lw.y + (double)lb.y;
            a0[g*4+2] = (a0[g*4+2] - m0) * r0 * (double)lw.z + (double)lb.z;
            a0[g*4+3] = (a0[g*4+3] - m0) * r0 * (double)lw.w + (double)lb.w;
          }
          for (int cc = 0; cc < 8; ++cc) {
            const int c = col0 + cc;
            const float4* pr = (const float4*)(A.Wih1 + (size_t)c * 1024);
            const float4* pz = (const float4*)(A.Wih1 + (size_t)(c + 1024) * 1024);
            const float4* pn = (const float4*)(A.Wih1 + (size_t)(c + 2048) * 1024);
            double ar = 0.0, az = 0.0, an_ = 0.0;
#pragma unroll
            for (int g = 0; g < 4; ++g) {
              const float4 wr = pr[g*64 + l], wz = pz[g*64 + l], wn = pn[g*64 + l];
              ar = fma(a0[g*4+0], (double)wr.x, ar); ar = fma(a0[g*4+1], (double)wr.y, ar);
              ar = fma(a0[g*4+2], (double)wr.z, ar); ar = fma(a0[g*4+3], (double)wr.w, ar);
              az = fma(a0[g*4+0], (double)wz.x, az); az = fma(a0[g*4+1], (double)wz.y, az);
              az = fma(a0[g*4+2], (double)wz.z, az); az = fma(a0[g*4+3], (double)wz.w, az);
              an_ = fma(a0[g*4+0], (double)wn.x, an_); an_ = fma(a0[g*4+1], (double)wn.y, an_);
              an_ = fma(a0[g*4+2], (double)wn.z, an_); an_ = fma(a0[g*4+3], (double)wn.w, an_);
            }
#pragma unroll
            for (int mk = 1; mk <= 32; mk <<= 1) {
              ar += __shfl_xor(ar, mk); az += __shfl_xor(az, mk); an_ += __shfl_xor(an_, mk);
            }
            if (l == cc) { sIr = ar; sIz = az; sIn = an_; }
          }
        }
        // ---- pass B: a1 = LN1(h1(t-1)), Whh1 dots ----
        if (t > 0) {
          double a1[16];
          const double* hp = A.h1ring + (size_t)((t - 1) & 1) * 16384 + w * 1024;
          double s = 0.0, q = 0.0;
#pragma unroll
          for (int g = 0; g < 4; ++g) {
            const double2 x0 = *(const double2*)(hp + g * 256 + l * 4);
            const double2 x1 = *(const double2*)(hp + g * 256 + l * 4 + 2);
            a1[g*4+0] = x0.x; a1[g*4+1] = x0.y; a1[g*4+2] = x1.x; a1[g*4+3] = x1.y;
            s += x0.x + x0.y + x1.x + x1.y;
            q += x0.x*x0.x + x0.y*x0.y + x1.x*x1.x + x1.y*x1.y;
          }
#pragma unroll
          for (int mk = 1; mk <= 32; mk <<= 1) { s += __shfl_xor(s, mk); q += __shfl_xor(q, mk); }
          m1 = s * (1.0 / 1024.0);
          r1 = 1.0 / sqrt(q * (1.0 / 1024.0) - m1 * m1 + LN_EPS);
#pragma unroll
          for (int g = 0; g < 4; ++g) {
            const float4 lw = *(const float4*)(A.ln1w + g * 256 + l * 4);
            const float4 lb = *(const float4*)(A.ln1b + g * 256 + l * 4);
            a1[g*4+0] = (a1[g*4+0] - m1) * r1 * (double)lw.x + (double)lb.x;
            a1[g*4+1] = (a1[g*4+1] - m1) * r1 * (double)lw.y + (double)lb.y;
            a1[g*4+2] = (a1[g*4+2] - m1) * r1 * (double)lw.z + (double)lb.z;
            a1[g*4+3] = (a1[g*4+3] - m1) * r1 * (double)lw.w + (double)lb.w;
          }
          for (int cc = 0; cc < 8; ++cc) {
            const int c = col0 + cc;
            const float4* pr = (const float4*)(A.Whh1 + (size_t)c * 1024);
            const float4* pz = (const float4*)(A.Whh1 + (size_t)(c + 1024) * 1024);
            const float4* pn = (const float4*)(A.Whh1 + (size_t)(c + 2048) * 1024);
            double ar = 0.0, az = 0.0, an_ = 0.0;
#pragma unroll
            for (int g = 0; g < 4; ++g) {
              const float4 wr = pr[g*64 + l], wz = pz[g*64 + l], wn = pn[g*64 + l];
              ar = fma(a1[g*4+0], (double)wr.x, ar); ar = fma(a1[g*4+1], (double)wr.y, ar);
              ar = fma(a1[g*4+2], (double)wr.z, ar); ar = fma(a1[g*4+3], (double)wr.w, ar);
              az = fma(a1[g*4+0], (double)wz.x, az); az = fma(a1[g*4+1], (double)wz.y, az);
              az = fma(a1[g*4+2], (double)wz.z, az); az = fma(a1[g*4+3], (double)wz.w, az);
              an_ = fma(a1[g*4+0], (double)wn.x, an_); an_ = fma(a1[g*4+1], (double)wn.y, an_);
              an_ = fma(a1[g*4+2], (double)wn.z, an_); an_ = fma(a1[g*4+3], (double)wn.w, an_);
            }
#pragma unroll
            for (int mk = 1; mk <= 32; mk <<= 1) {
              ar += __shfl_xor(ar, mk); az += __shfl_xor(az, mk); an_ += __shfl_xor(an_, mk);
            }
            if (l == cc) { sHr = ar; sHz = az; sHn = an_; }
          }
        }
        if (l < 8) {
          const int c = col0 + l;
          const double gir = sIr + (double)A.bih1[c];
          const double giz = sIz + (double)A.bih1[c + 1024];
          const double gin = sIn + (double)A.bih1[c + 2048];
          const double ghr = sHr + (double)A.bhh1[c];
          const double ghz = sHz + (double)A.bhh1[c + 1024];
          const double ghn = sHn + (double)A.bhh1[c + 2048];
          const double rg = 1.0 / (1.0 + exp(-(gir + ghr)));
          const double zg = 1.0 / (1.0 + exp(-(giz + ghz)));
          const double ng = tanh(gin + rg * ghn);
          double hprev = 0.0;
          if (t > 0) {
            const double praw = A.h1ring[(size_t)((t - 1) & 1) * 16384 + w * 1024 + c];
            hprev = (praw - m1) * r1 * (double)A.ln1w[c] + (double)A.ln1b[c];
          }
          const double hnew = (1.0 - zg) * ng + zg * hprev;
          A.h1ring[(size_t)(t & 1) * 16384 + w * 1024 + c] = hnew;
          A.h1hist[((size_t)t * 16 + w) * 1024 + c] = (float)hnew;
        }
      }
    }

    // ---------- grid barrier ----------
    __syncthreads();
    if (tid == 0) {
      __threadfence();
      __hip_atomic_fetch_add(A.bar, 1, __ATOMIC_ACQ_REL, __HIP_MEMORY_SCOPE_AGENT);
      const int target = NBLK * (p + 1);
      while (__hip_atomic_load(A.bar, __ATOMIC_ACQUIRE, __HIP_MEMORY_SCOPE_AGENT) < target) {
        __builtin_amdgcn_s_sleep(2);
      }
      __threadfence();
    }
    __syncthreads();
  }
}

// ---------------- batched head pre-proj (byte-identical to round 7/8) ----------------
__launch_bounds__(512, 2)
__global__ void k_headpre(const float* __restrict__ h1hist, const float* __restrict__ ln1w,
                          const float* __restrict__ ln1b, const float* __restrict__ W1,
                          const float* __restrict__ b1, short* __restrict__ araw) {
  const int tid = threadIdx.x;
  const int row = tid >> 5, ks = tid & 31;
  const size_t m = (size_t)blockIdx.x * 16 + row;
  const float* hp = h1hist + m * 1024;
  float a[32];
  float s = 0.f, q = 0.f;
#pragma unroll
  for (int g = 0; g < 8; ++g) {
    const float4 v = *(const float4*)(hp + g * 128 + ks * 4);
    a[g*4+0] = v.x; a[g*4+1] = v.y; a[g*4+2] = v.z; a[g*4+3] = v.w;
    s += v.x + v.y + v.z + v.w;
    q += v.x * v.x + v.y * v.y + v.z * v.z + v.w * v.w;
  }
#pragma unroll
  for (int mk = 1; mk <= 16; mk <<= 1) { s += __shfl_xor(s, mk); q += __shfl_xor(q, mk); }
  const float mn = s * (1.f / 1024.f);
  const float rs = rsqrtf(q * (1.f / 1024.f) - mn * mn + 1e-5f);
#pragma unroll
  for (int g = 0; g < 8; ++g) {
    const float4 lw = *(const float4*)(ln1w + g * 128 + ks * 4);
    const float4 lb = *(const float4*)(ln1b + g * 128 + ks * 4);
    a[g*4+0] = (a[g*4+0] - mn) * rs * lw.x + lb.x;
    a[g*4+1] = (a[g*4+1] - mn) * rs * lw.y + lb.y;
    a[g*4+2] = (a[g*4+2] - mn) * rs * lw.z + lb.z;
    a[g*4+3] = (a[g*4+3] - mn) * rs * lw.w + lb.w;
  }
  for (int c = 0; c < 1024; ++c) {
    const float4* wp = (const float4*)(W1 + (size_t)c * 1024);
    float acc = 0.f;
#pragma unroll
    for (int g = 0; g < 8; ++g) {
      const float4 w = wp[g * 32 + ks];
      acc = fmaf(a[g*4+0], w.x, acc); acc = fmaf(a[g*4+1], w.y, acc);
      acc = fmaf(a[g*4+2], w.z, acc); acc = fmaf(a[g*4+3], w.w, acc);
    }
#pragma unroll
    for (int mk = 1; mk <= 16; mk <<= 1) acc += __shfl_xor(acc, mk);
    if (ks == 0) {
      const float y = acc + b1[c];
      araw[m * 1024 + c] = f2bf(y > 0.f ? y : 0.01f * y);
    }
  }
}

// ---------------- head GEMM (byte-identical to rounds 6-8) ----------------
__global__ void k_head(const short* __restrict__ araw, const float* __restrict__ W2,
                       const float* __restrict__ ln2w, const float* __restrict__ ln2b,
                       const float* __restrict__ b2, float* __restrict__ C) {
  __shared__ __align__(16) short As[128 * 64];
  __shared__ __align__(16) short Bs[128 * 64];
  __shared__ float rowm[128], rowr[128];
  __shared__ float lnw_s[1024], lnb_s[1024];
  __shared__ float ps[256], pq[256];
  const int tid = threadIdx.x;
  const long brow = (long)blockIdx.y * 128;
  const long bcol = (long)blockIdx.x * 128;

  for (int i = tid; i < 1024; i += 256) { lnw_s[i] = ln2w[i]; lnb_s[i] = ln2b[i]; }
  {
    const int r2 = tid >> 1, hf = tid & 1;
    const short* ap = araw + (brow + r2) * 1024 + hf * 512;
    float s = 0.f, q = 0.f;
    for (int j = 0; j < 512; j += 8) {
      const bf16x8 v = *(const bf16x8*)(ap + j);
#pragma unroll
      for (int e = 0; e < 8; ++e) { const float x = bf2f(v[e]); s += x; q += x * x; }
    }
    ps[tid] = s; pq[tid] = q;
  }
  __syncthreads();
  if (tid < 128) {
    const float s = ps[2 * tid] + ps[2 * tid + 1];
    const float q = pq[2 * tid] + pq[2 * tid + 1];
    const float m = s * (1.f / 1024.f);
    rowm[tid] = m;
    rowr[tid] = rsqrtf(q * (1.f / 1024.f) - m * m + 1e-5f);
  }
  __syncthreads();

  const int l = tid & 63;
  const int w = tid >> 6;
  const int wm = w >> 1, wn = w & 1;
  const int lane15 = l & 15, lgrp = l >> 4;
  f32x4 zero4 = {0.f, 0.f, 0.f, 0.f};
  f32x4 acc[4][4];
#pragma unroll
  for (int ri = 0; ri < 4; ++ri)
#pragma unroll
    for (int ci = 0; ci < 4; ++ci) acc[ri][ci] = zero4;

  for (int k0 = 0; k0 < 1024; k0 += 64) {
    __syncthreads();
#pragma unroll
    for (int i = 0; i < 4; ++i) {
      const int c = tid + i * 256;
      const int r = c >> 3, cc = c & 7;
      const int k = k0 + cc * 8;
      {
        const bf16x8 v = *(const bf16x8*)(araw + (brow + r) * 1024 + k);
        const float mm = rowm[r], rr = rowr[r];
        bf16x8 o;
#pragma unroll
        for (int e = 0; e < 8; ++e)
          o[e] = f2bf((bf2f(v[e]) - mm) * rr * lnw_s[k + e] + lnb_s[k + e]);
        *(bf16x8*)&As[r * 64 + cc * 8] = o;
      }
      {
        const float4* bp = (const float4*)(W2 + (bcol + r) * 1024 + k);
        const float4 v0 = bp[0], v1 = bp[1];
        bf16x8 o;
        o[0] = f2bf(v0.x); o[1] = f2bf(v0.y); o[2] = f2bf(v0.z); o[3] = f2bf(v0.w);
        o[4] = f2bf(v1.x); o[5] = f2bf(v1.y); o[6] = f2bf(v1.z); o[7] = f2bf(v1.w);
        *(bf16x8*)&Bs[r * 64 + cc * 8] = o;
      }
    }
    __syncthreads();
#pragma unroll
    for (int kk = 0; kk < 2; ++kk) {
      const int ko = kk * 32 + lgrp * 8;
      bf16x8 av[4], bv[4];
#pragma unroll
      for (int ri = 0; ri < 4; ++ri) av[ri] = *(const bf16x8*)&As[(wm * 64 + ri * 16 + lane15) * 64 + ko];
#pragma unroll
      for (int ci = 0; ci < 4; ++ci) bv[ci] = *(const bf16x8*)&Bs[(wn * 64 + ci * 16 + lane15) * 64 + ko];
#pragma unroll
      for (int ri = 0; ri < 4; ++ri)
#pragma unroll
        for (int ci = 0; ci < 4; ++ci) acc[ri][ci] = mfma16(av[ri], bv[ci], acc[ri][ci]);
    }
  }
#pragma unroll
  for (int ri = 0; ri < 4; ++ri)
#pragma unroll
    for (int ci = 0; ci < 4; ++ci)
#pragma unroll
      for (int i = 0; i < 4; ++i) {
        const long mrow = brow + wm * 64 + ri * 16 + lgrp * 4 + i;
        const long ncol = bcol + wn * 64 + ci * 16 + lane15;
        const int tq = (int)(mrow >> 4), b = (int)(mrow & 15);
        C[(size_t)b * TT * VOCAB + (size_t)tq * VOCAB + ncol] = acc[ri][ci][i] + b2[ncol];
      }
}

// ---------------- host launch ----------------
extern "C" void kernel_launch(void* const* d_in, const int* in_sizes, int n_in,
                              void* d_out, int out_size, void* d_ws, size_t ws_size,
                              hipStream_t stream) {
  const int* input = (const int*)d_in[0];
  const float* embd = (const float*)d_in[1];
  const float* Wih0 = (const float*)d_in[2];
  const float* Whh0 = (const float*)d_in[3];
  const float* bih0 = (const float*)d_in[4];
  const float* bhh0 = (const float*)d_in[5];
  const float* ln0w = (const float*)d_in[6];
  const float* ln0b = (const float*)d_in[7];
  const float* Wih1 = (const float*)d_in[8];
  const float* Whh1 = (const float*)d_in[9];
  const float* bih1 = (const float*)d_in[10];
  const float* bhh1 = (const float*)d_in[11];
  const float* ln1w = (const float*)d_in[12];
  const float* ln1b = (const float*)d_in[13];
  const float* W1 = (const float*)d_in[14];
  const float* b1 = (const float*)d_in[15];
  const float* ln2w = (const float*)d_in[16];
  const float* ln2b = (const float*)d_in[17];
  const float* W2 = (const float*)d_in[18];
  const float* b2 = (const float*)d_in[19];
  float* out = (float*)d_out;

  // ws (25.4 MB): rings + h1 history + araw + barrier.
  char* ws = (char*)d_ws;
  size_t off = 0;
  auto alloc = [&](size_t bytes) -> char* {
    char* p = ws + off;
    off = (off + bytes + 255) & ~(size_t)255;
    return p;
  };
  double* h0ring = (double*)alloc(2ull * 16 * 1024 * 8);
  double* h1ring = (double*)alloc(2ull * 16 * 1024 * 8);
  float* h1hist = (float*)alloc(4096ull * 1024 * 4);
  short* araw = (short*)alloc(4096ull * 1024 * 2);
  int* bar = (int*)alloc(256);

  hipMemsetAsync(bar, 0, 256, stream);

  // gi0 (100.7 MB f64) in d_out-as-scratch: fully consumed by k_recur; k_head
  // then overwrites every byte of d_out.
  double* gi0 = (double*)d_out;

  k_gi0<<<4096, 256, 0, stream>>>(input, embd, Wih0, bih0, gi0);

  SP A;
  A.Whh0 = Whh0; A.bhh0 = bhh0; A.ln0w = ln0w; A.ln0b = ln0b;
  A.Wih1 = Wih1; A.Whh1 = Whh1; A.bih1 = bih1; A.bhh1 = bhh1;
  A.ln1w = ln1w; A.ln1b = ln1b;
  A.gi0 = gi0; A.h0ring = h0ring; A.h1ring = h1ring; A.h1hist = h1hist;
  A.bar = bar;
  k_recur<<<NBLK, 1024, 0, stream>>>(A);

  k_headpre<<<256, 512, 0, stream>>>(h1hist, ln1w, ln1b, W1, b1, araw);

  k_head<<<dim3(250, 32), 256, 0, stream>>>(araw, W2, ln2w, ln2b, b2, out);
}